// Round 2
// baseline (426.078 us; speedup 1.0000x reference)
//
#include <hip/hip_runtime.h>
#include <cstdint>
#include <cstddef>

#define M_DIM 8192
#define N_DIM 4096
#define K_DIM 4096

// fallback-path tile (128x128, verified)
#define BM 128
#define BN 128
#define BK 128

// fast-path 8-phase tile
#define BM2 256
#define BN2 256
#define BK2 128
#define NKT (K_DIM / BK2)   // 32

typedef int int32x4  __attribute__((ext_vector_type(4)));
typedef int int32x16 __attribute__((ext_vector_type(16)));

// ws layout:
//   int32 header (64 KB):
//     [0] = flagA (1 -> source already packed int8, 0 -> widened int32)
//     [1] = flagB
//     [16 .. 16+N)      qb (shifted bias)
//     [16+N .. 16+2N)   int_scale
//     [16+2N .. 16+3N)  frac_bits
//   byte 65536:           A8  (M*K int8)  (used when flagA==0)
//   byte 65536 + M*K:     W8  (N*K int8)  (used when flagB==0)

typedef __attribute__((address_space(1))) const void* gas_cptr;
typedef __attribute__((address_space(3))) void* las_ptr;

__device__ __forceinline__ void async_copy16(const void* g, void* l) {
    __builtin_amdgcn_global_load_lds((gas_cptr)g, (las_ptr)l, 16, 0, 0);
}

__device__ __forceinline__ int32x4 pack16(const int* p) {
    const int32x4* v = (const int32x4*)p;
    int32x4 w0 = v[0], w1 = v[1], w2 = v[2], w3 = v[3];
    int32x4 r;
    r.x = (w0.x & 0xFF) | ((w0.y & 0xFF) << 8) | ((w0.z & 0xFF) << 16) | (w0.w << 24);
    r.y = (w1.x & 0xFF) | ((w1.y & 0xFF) << 8) | ((w1.z & 0xFF) << 16) | (w1.w << 24);
    r.z = (w2.x & 0xFF) | ((w2.y & 0xFF) << 8) | ((w2.z & 0xFF) << 16) | (w2.w << 24);
    r.w = (w3.x & 0xFF) | ((w3.y & 0xFF) << 8) | ((w3.z & 0xFF) << 16) | (w3.w << 24);
    return r;
}

__global__ void ql_detect_kernel(const int* a, const int* b, int* ws) {
    int t = threadIdx.x;  // 64 threads
    int fa = 0, fb = 0;
    for (int i = t; i < 4096; i += 64) {
        int va = a[i]; if (va > 127 || va < -128) fa = 1;
        int vb = b[i]; if (vb > 127 || vb < -128) fb = 1;
    }
    unsigned long long ba = __ballot(fa);
    unsigned long long bb = __ballot(fb);
    if (t == 0) { ws[0] = ba ? 1 : 0; ws[1] = bb ? 1 : 0; }
}

// Merged pack: W segment then A segment, one launch. Early-exit when packed.
__global__ __launch_bounds__(256)
void ql_pack2_kernel(const void* wsrc, int* wdst, const void* asrc, int* adst,
                     const int* ws, long ndwW, long ndwA) {
    const int fA = __builtin_amdgcn_readfirstlane(ws[0]);
    const int fW = __builtin_amdgcn_readfirstlane(ws[1]);
    const long nW = fW ? 0 : ndwW;
    const long nA = fA ? 0 : ndwA;
    const long total = nW + nA;
    const long stride = (long)gridDim.x * 256;
    for (long c = (long)blockIdx.x * 256 + threadIdx.x; c < total; c += stride) {
        if (c < nW) {
            int32x4 v = ((const int32x4*)wsrc)[c];
            wdst[c] = (v.x & 0xFF) | ((v.y & 0xFF) << 8) | ((v.z & 0xFF) << 16) | (v.w << 24);
        } else {
            const long ca = c - nW;
            int32x4 v = ((const int32x4*)asrc)[ca];
            adst[ca] = (v.x & 0xFF) | ((v.y & 0xFF) << 8) | ((v.z & 0xFF) << 16) | (v.w << 24);
        }
    }
}

// Fast-path prep: rowsum + requant params from flag-selected int8 weights.
__global__ void ql_prep8_kernel(const void* worig, const int8_t* w8p, const int* qbias,
                                const float* wscale, int* ws) {
    const int fb = __builtin_amdgcn_readfirstlane(ws[1]);
    const int8_t* w8 = fb ? (const int8_t*)worig : w8p;

    const int lane = threadIdx.x & 63;
    const int wid  = threadIdx.x >> 6;
    const int n = blockIdx.x * 4 + wid;

    const int32x4* row = (const int32x4*)(w8 + (size_t)n * K_DIM);
    int s = 0;
    for (int c = lane; c < K_DIM / 16; c += 64) {
        int32x4 v = row[c];
#pragma unroll
        for (int j = 0; j < 4; ++j) {
            int w = (j == 0) ? v.x : (j == 1) ? v.y : (j == 2) ? v.z : v.w;
            s += (int)(int8_t)(w) + (int)(int8_t)(w >> 8)
               + (int)(int8_t)(w >> 16) + (w >> 24);
        }
    }
#pragma unroll
    for (int off = 32; off > 0; off >>= 1) s += __shfl_down(s, off, 64);

    if (lane == 0) {
        ws[16 + n] = qbias[n] + 3 * s;                       // qbias - rowsum*Zin, Zin=-3
        float folded = (0.05f * wscale[n]) / 0.1f;           // in (0,1)
        int fbits = (int)(7.0f - ceilf(log2f(folded)));
        int isc = (int)rintf(folded * exp2f((float)fbits));  // nearest-even == np.round
        ws[16 + N_DIM + n] = isc;
        ws[16 + 2 * N_DIM + n] = fbits;
    }
}

// Fallback prep (ws too small): reads original W, flag-based.
__global__ void ql_prep_kernel(const void* wptr, const int* qbias,
                               const float* wscale, int* ws) {
    const int lane = threadIdx.x & 63;
    const int wid  = threadIdx.x >> 6;
    const int n = blockIdx.x * 4 + wid;
    const int b8 = __builtin_amdgcn_readfirstlane(ws[1]);

    int s = 0;
    if (b8) {
        const int32x4* row = (const int32x4*)((const int8_t*)wptr + (size_t)n * K_DIM);
        for (int c = lane; c < K_DIM / 16; c += 64) {
            int32x4 v = row[c];
#pragma unroll
            for (int j = 0; j < 4; ++j) {
                int w = (j == 0) ? v.x : (j == 1) ? v.y : (j == 2) ? v.z : v.w;
                s += (int)(int8_t)(w) + (int)(int8_t)(w >> 8)
                   + (int)(int8_t)(w >> 16) + (w >> 24);
            }
        }
    } else {
        const int32x4* row = (const int32x4*)((const int*)wptr + (size_t)n * K_DIM);
        for (int c = lane; c < K_DIM / 4; c += 64) {
            int32x4 v = row[c];
            s += v.x + v.y + v.z + v.w;
        }
    }
#pragma unroll
    for (int off = 32; off > 0; off >>= 1) s += __shfl_down(s, off, 64);

    if (lane == 0) {
        ws[16 + n] = qbias[n] + 3 * s;
        float folded = (0.05f * wscale[n]) / 0.1f;
        int fbits = (int)(7.0f - ceilf(log2f(folded)));
        int isc = (int)rintf(folded * exp2f((float)fbits));
        ws[16 + N_DIM + n] = isc;
        ws[16 + 2 * N_DIM + n] = fbits;
    }
}

// Fallback epilogue (128x128 path): requantize acc tile and store int32.
__device__ __forceinline__ void ql_epilogue(int32x4 acc[4][4], const int* ws,
                                            int* out, int bm, int bn,
                                            int wm, int wn, int qm, int qh) {
    const int* qb  = ws + 16;
    const int* isc = ws + 16 + N_DIM;
    const int* fbt = ws + 16 + 2 * N_DIM;
#pragma unroll
    for (int j = 0; j < 4; ++j) {
        const int n_g = bn * BN + wn + j * 16 + qm;
        const int b0 = qb[n_g];
        const int s0 = isc[n_g];
        const int f0 = fbt[n_g];
#pragma unroll
        for (int i = 0; i < 4; ++i) {
            const int m_base = bm * BM + wm + i * 16 + qh * 4;
#pragma unroll
            for (int r = 0; r < 4; ++r) {
                int v = ((r == 0) ? acc[i][j].x : (r == 1) ? acc[i][j].y
                        : (r == 2) ? acc[i][j].z : acc[i][j].w) + b0;
                long long p = (long long)v * (long long)s0;
                int o = (int)(p >> f0) - 5;            // + OUTPUT_ZERO_POINT (-5)
                o = o < -128 ? -128 : (o > 127 ? 127 : o);
                out[(size_t)(m_base + r) * N_DIM + n_g] = o;
            }
        }
    }
}

// ---------------- fast path: 256x256 8-phase GEMM, 32x32x32 i8 MFMA ----------------
// LDS image identical to R1 (row-major 128-B rows, per-row XOR-swizzled 16-B chunks).
// Per tile T (buffer BUF = T&1), phases:
//   ph1: read A-lo (8) + B-n0 (4); stage (T+1).A1 -> LA[BUF^1]
//   ph2: read B-n1 (4);            stage (T+1).B1 -> LB[BUF^1]
//   ph3: read A-hi (8);            stage (T+2).B0 -> LB[BUF]   (B reads drained at ph2-MFMA)
//   ph4: (no reads);               stage (T+2).A0 -> LA[BUF]   (A reads drained at ph3-MFMA)
// vmcnt(4) at tile top leaves only (T+1).{B0,A0} in flight; last tile drains vmcnt(0).

#define LOAD_AF(BUF, MH) do { \
    _Pragma("unroll") for (int ml = 0; ml < 2; ++ml) \
    _Pragma("unroll") for (int kc = 0; kc < 4; ++kc) \
        af[ml][kc] = LA[BUF][baseAe[kc] + (MH) * 512 + ml * 256]; \
} while (0)

#define LOAD_BF(BUF, NH, DST) do { \
    _Pragma("unroll") for (int kc = 0; kc < 4; ++kc) \
        DST[kc] = LB[BUF][baseBe[kc] + (NH) * 256]; \
} while (0)

#define MFMA_QUAD(MH, NH, BF) do { \
    __builtin_amdgcn_s_setprio(1); \
    _Pragma("unroll") for (int kc = 0; kc < 4; ++kc) \
    _Pragma("unroll") for (int ml = 0; ml < 2; ++ml) \
        acc[(MH) * 2 + ml][NH] = __builtin_amdgcn_mfma_i32_32x32x32_i8( \
            af[ml][kc], BF[kc], acc[(MH) * 2 + ml][NH], 0, 0, 0); \
    __builtin_amdgcn_s_setprio(0); \
} while (0)

#define STAGE_A(BUF, H, TT) do { \
    async_copy16(gA + (size_t)(TT) * 128 + (H) * 524288,          &LA[BUF][(H) * 1024 + t]); \
    async_copy16(gA + (size_t)(TT) * 128 + (H) * 524288 + 262144, &LA[BUF][(H) * 1024 + 512 + t]); \
} while (0)

#define STAGE_B(BUF, H, TT) do { \
    async_copy16(gB + (size_t)(TT) * 128 + (H) * 524288,          &LB[BUF][(H) * 1024 + t]); \
    async_copy16(gB + (size_t)(TT) * 128 + (H) * 524288 + 262144, &LB[BUF][(H) * 1024 + 512 + t]); \
} while (0)

#define TILE_BODY(BUF, TT, VMC) do { \
    asm volatile("s_waitcnt vmcnt(" #VMC ")"); \
    __builtin_amdgcn_s_barrier(); \
    LOAD_AF(BUF, 0); \
    LOAD_BF(BUF, 0, bf0); \
    if ((TT) + 1 < NKT) { STAGE_A(BUF ^ 1, 1, (TT) + 1); } \
    __builtin_amdgcn_s_barrier(); \
    MFMA_QUAD(0, 0, bf0); \
    __builtin_amdgcn_s_barrier(); \
    LOAD_BF(BUF, 1, bf1); \
    if ((TT) + 1 < NKT) { STAGE_B(BUF ^ 1, 1, (TT) + 1); } \
    __builtin_amdgcn_s_barrier(); \
    MFMA_QUAD(0, 1, bf1); \
    __builtin_amdgcn_s_barrier(); \
    LOAD_AF(BUF, 1); \
    if ((TT) + 2 < NKT) { STAGE_B(BUF, 0, (TT) + 2); } \
    __builtin_amdgcn_s_barrier(); \
    MFMA_QUAD(1, 0, bf0); \
    __builtin_amdgcn_s_barrier(); \
    if ((TT) + 2 < NKT) { STAGE_A(BUF, 0, (TT) + 2); } \
    __builtin_amdgcn_s_barrier(); \
    MFMA_QUAD(1, 1, bf1); \
} while (0)

__global__ __launch_bounds__(512, 2)
void ql_gemm8_kernel(const void* a0, const int8_t* a8,
                     const void* b0, const int8_t* w8,
                     const int* ws, int* out) {
    __shared__ int32x4 LA[2][2048];   // 2 x 32 KB
    __shared__ int32x4 LB[2][2048];   // 2 x 32 KB (total 128 KB)

    const int fa = __builtin_amdgcn_readfirstlane(ws[0]);
    const int fb = __builtin_amdgcn_readfirstlane(ws[1]);
    const int8_t* aptr = fa ? (const int8_t*)a0 : a8;
    const int8_t* bptr = fb ? (const int8_t*)b0 : w8;

    const int t    = threadIdx.x;     // 512 threads = 8 waves
    const int lane = t & 63;
    const int wid  = t >> 6;          // 0..7
    const int wr   = wid >> 2;        // 0..1  M-half (128 rows)
    const int wc   = wid & 3;         // 0..3  N-quarter (64 cols)
    const int l31  = lane & 31;
    const int hi   = lane >> 5;

    const int bn = blockIdx.x;        // N/256 = 16
    const int bm = blockIdx.y;        // M/256 = 32
    const int arow0 = bm * BM2;
    const int brow0 = bn * BN2;

    // Hoisted LDS frag bases (element units of int32x4), one per 32-B k-chunk kc.
    // row&7 == lane&7 for every frag row (all row bases are multiples of 8/32).
    int baseAe[4], baseBe[4];
#pragma unroll
    for (int kc = 0; kc < 4; ++kc) {
        const int phys = (kc * 2 + hi) ^ (lane & 7);
        baseAe[kc] = (wr * 128 + l31) * 8 + phys;
        baseBe[kc] = (wc * 64  + l31) * 8 + phys;
    }

    // Hoisted global stage bases: chunk c = h*1024 + r*512 + t; row = c>>3,
    // phys col = t&7, logical col = (t&7) ^ (row&7) with row&7 = (t>>3)&7 for both r.
    const int colg = (t & 7) ^ ((t >> 3) & 7);
    const int8_t* gA = aptr + (size_t)(arow0 + (t >> 3)) * K_DIM + colg * 16;
    const int8_t* gB = bptr + (size_t)(brow0 + (t >> 3)) * K_DIM + colg * 16;

    int32x16 acc[4][2] = {};
    int32x4 af[2][4], bf0[4], bf1[4];

    // prologue: T0 full tile + T1 lo-halves (12 loads/thread)
    STAGE_A(0, 0, 0); STAGE_B(0, 0, 0);
    STAGE_A(0, 1, 0); STAGE_B(0, 1, 0);
    STAGE_A(1, 0, 1); STAGE_B(1, 0, 1);

#pragma unroll 1
    for (int T = 0; T < NKT - 4; T += 2) {
        TILE_BODY(0, T, 4);
        TILE_BODY(1, T + 1, 4);
    }
    TILE_BODY(0, NKT - 4, 4);
    TILE_BODY(1, NKT - 3, 4);
    TILE_BODY(0, NKT - 2, 4);
    TILE_BODY(1, NKT - 1, 0);

    // epilogue: requantize + store (C/D map: col=lane&31, row=(reg&3)+8*(reg>>2)+4*hi)
    const int* qb  = ws + 16;
    const int* isc = ws + 16 + N_DIM;
    const int* fbt = ws + 16 + 2 * N_DIM;
#pragma unroll
    for (int j = 0; j < 2; ++j) {
        const int n_g = bn * BN2 + wc * 64 + j * 32 + l31;
        const int b0r = qb[n_g];
        const int s0r = isc[n_g];
        const int f0r = fbt[n_g];
#pragma unroll
        for (int i = 0; i < 4; ++i) {
            const int m0 = bm * BM2 + wr * 128 + i * 32 + hi * 4;
#pragma unroll
            for (int reg = 0; reg < 16; ++reg) {
                const int row = (reg & 3) + 8 * (reg >> 2);
                int v = acc[i][j][reg] + b0r;
                long long p = (long long)v * (long long)s0r;
                int o = (int)(p >> f0r) - 5;           // + OUTPUT_ZERO_POINT (-5)
                o = o < -128 ? -128 : (o > 127 ? 127 : o);
                out[(size_t)(m0 + row) * N_DIM + n_g] = o;
            }
        }
    }
}

// Fallback (ws too small): verified 128x128 kernel, packs in-loop.
__global__ __launch_bounds__(256)
void ql_gemm_fb_kernel(const void* aptr, const void* bptr, const int* ws, int* out) {
    __shared__ int32x4 Als[BM * BK / 16];
    __shared__ int32x4 Bls[BN * BK / 16];

    const int a8 = __builtin_amdgcn_readfirstlane(ws[0]);
    const int b8 = __builtin_amdgcn_readfirstlane(ws[1]);

    const int t    = threadIdx.x;
    const int lane = t & 63;
    const int wid  = t >> 6;
    const int bn = blockIdx.x;
    const int bm = blockIdx.y;

    const int wm = (wid >> 1) * 64;
    const int wn = (wid & 1) * 64;
    const int qm = lane & 15;
    const int qh = lane >> 4;

    int32x4 acc[4][4] = {};

    for (int kt = 0; kt < K_DIM / BK; ++kt) {
        __syncthreads();
        const int k0 = kt * BK;
#pragma unroll
        for (int r = 0; r < 4; ++r) {
            const int c    = r * 256 + t;
            const int row  = c >> 3;
            const int colg = (c & 7) ^ (row & 7);
            const size_t offA = (size_t)(bm * BM + row) * K_DIM + k0 + colg * 16;
            const size_t offB = (size_t)(bn * BN + row) * K_DIM + k0 + colg * 16;
            if (a8) async_copy16((const int8_t*)aptr + offA, &Als[c]);
            else    Als[c] = pack16((const int*)aptr + offA);
            if (b8) async_copy16((const int8_t*)bptr + offB, &Bls[c]);
            else    Bls[c] = pack16((const int*)bptr + offB);
        }
        __syncthreads();

#pragma unroll
        for (int s = 0; s < 2; ++s) {
            const int colk = s * 4 + qh;
            int32x4 af[4], bf[4];
#pragma unroll
            for (int i = 0; i < 4; ++i) {
                const int ra = wm + i * 16 + qm;
                const int rb = wn + i * 16 + qm;
                af[i] = Als[ra * 8 + (colk ^ (ra & 7))];
                bf[i] = Bls[rb * 8 + (colk ^ (rb & 7))];
            }
#pragma unroll
            for (int i = 0; i < 4; ++i)
#pragma unroll
                for (int j = 0; j < 4; ++j)
                    acc[i][j] = __builtin_amdgcn_mfma_i32_16x16x64_i8(
                        af[i], bf[j], acc[i][j], 0, 0, 0);
        }
    }
    ql_epilogue(acc, ws, out, bm, bn, wm, wn, qm, qh);
}

extern "C" void kernel_launch(void* const* d_in, const int* in_sizes, int n_in,
                              void* d_out, int out_size, void* d_ws, size_t ws_size,
                              hipStream_t stream) {
    const void* qin    = d_in[0];
    const void* qwt    = d_in[1];
    const int* qbias   = (const int*)d_in[2];
    const float* wscal = (const float*)d_in[3];
    int* ws  = (int*)d_ws;
    int* out = (int*)d_out;

    hipLaunchKernelGGL(ql_detect_kernel, dim3(1), dim3(64), 0, stream,
                       (const int*)qin, (const int*)qwt, ws);

    const size_t need = 65536 + (size_t)M_DIM * K_DIM + (size_t)N_DIM * K_DIM;
    if (ws_size >= need) {
        int8_t* a8 = (int8_t*)d_ws + 65536;
        int8_t* w8 = a8 + (size_t)M_DIM * K_DIM;
        const long ndwA = (long)M_DIM * K_DIM / 4;   // packed output dwords
        const long ndwW = (long)N_DIM * K_DIM / 4;
        const long ndwT = ndwA + ndwW;
        hipLaunchKernelGGL(ql_pack2_kernel, dim3((unsigned)(ndwT / (256 * 4))), dim3(256),
                           0, stream, qwt, (int*)w8, qin, (int*)a8, ws, ndwW, ndwA);
        hipLaunchKernelGGL(ql_prep8_kernel, dim3(N_DIM / 4), dim3(256), 0, stream,
                           qwt, w8, qbias, wscal, ws);
        hipLaunchKernelGGL(ql_gemm8_kernel, dim3(N_DIM / BN2, M_DIM / BM2), dim3(512),
                           0, stream, qin, a8, qwt, w8, ws, out);
    } else {
        hipLaunchKernelGGL(ql_prep_kernel, dim3(N_DIM / 4), dim3(256), 0, stream,
                           qwt, qbias, wscal, ws);
        hipLaunchKernelGGL(ql_gemm_fb_kernel, dim3(N_DIM / BN, M_DIM / BM), dim3(256), 0, stream,
                           qin, qwt, ws, out);
    }
}

// Round 3
// 414.412 us; speedup vs baseline: 1.0282x; 1.0282x over previous
//
#include <hip/hip_runtime.h>
#include <cstdint>
#include <cstddef>

#define M_DIM 8192
#define N_DIM 4096
#define K_DIM 4096

// fallback-path tile (128x128, verified)
#define BM 128
#define BN 128
#define BK 128

// fast-path tile
#define BM2 256
#define BN2 256
#define BK2 128
#define NKT (K_DIM / BK2)   // 32

typedef int int32x4  __attribute__((ext_vector_type(4)));
typedef int int32x16 __attribute__((ext_vector_type(16)));

// ws layout:
//   int32 header (64 KB):
//     [0] = flagA (1 -> source already packed int8, 0 -> widened int32)
//     [1] = flagB
//     [16 .. 16+N)      qb (shifted bias)
//     [16+N .. 16+2N)   int_scale
//     [16+2N .. 16+3N)  frac_bits
//   byte 65536:           A8  (M*K int8)  (used when flagA==0)
//   byte 65536 + M*K:     W8  (N*K int8)  (used when flagB==0)

typedef __attribute__((address_space(1))) const void* gas_cptr;
typedef __attribute__((address_space(3))) void* las_ptr;

__device__ __forceinline__ void async_copy16(const void* g, void* l) {
    __builtin_amdgcn_global_load_lds((gas_cptr)g, (las_ptr)l, 16, 0, 0);
}

__device__ __forceinline__ int32x4 pack16(const int* p) {
    const int32x4* v = (const int32x4*)p;
    int32x4 w0 = v[0], w1 = v[1], w2 = v[2], w3 = v[3];
    int32x4 r;
    r.x = (w0.x & 0xFF) | ((w0.y & 0xFF) << 8) | ((w0.z & 0xFF) << 16) | (w0.w << 24);
    r.y = (w1.x & 0xFF) | ((w1.y & 0xFF) << 8) | ((w1.z & 0xFF) << 16) | (w1.w << 24);
    r.z = (w2.x & 0xFF) | ((w2.y & 0xFF) << 8) | ((w2.z & 0xFF) << 16) | (w2.w << 24);
    r.w = (w3.x & 0xFF) | ((w3.y & 0xFF) << 8) | ((w3.z & 0xFF) << 16) | (w3.w << 24);
    return r;
}

__global__ void ql_detect_kernel(const int* a, const int* b, int* ws) {
    int t = threadIdx.x;  // 64 threads
    int fa = 0, fb = 0;
    for (int i = t; i < 4096; i += 64) {
        int va = a[i]; if (va > 127 || va < -128) fa = 1;
        int vb = b[i]; if (vb > 127 || vb < -128) fb = 1;
    }
    unsigned long long ba = __ballot(fa);
    unsigned long long bb = __ballot(fb);
    if (t == 0) { ws[0] = ba ? 1 : 0; ws[1] = bb ? 1 : 0; }
}

// Merged pack: W segment then A segment, one launch. Early-exit when packed.
__global__ __launch_bounds__(256)
void ql_pack2_kernel(const void* wsrc, int* wdst, const void* asrc, int* adst,
                     const int* ws, long ndwW, long ndwA) {
    const int fA = __builtin_amdgcn_readfirstlane(ws[0]);
    const int fW = __builtin_amdgcn_readfirstlane(ws[1]);
    const long nW = fW ? 0 : ndwW;
    const long nA = fA ? 0 : ndwA;
    const long total = nW + nA;
    const long stride = (long)gridDim.x * 256;
    for (long c = (long)blockIdx.x * 256 + threadIdx.x; c < total; c += stride) {
        if (c < nW) {
            int32x4 v = ((const int32x4*)wsrc)[c];
            wdst[c] = (v.x & 0xFF) | ((v.y & 0xFF) << 8) | ((v.z & 0xFF) << 16) | (v.w << 24);
        } else {
            const long ca = c - nW;
            int32x4 v = ((const int32x4*)asrc)[ca];
            adst[ca] = (v.x & 0xFF) | ((v.y & 0xFF) << 8) | ((v.z & 0xFF) << 16) | (v.w << 24);
        }
    }
}

// Fast-path prep: rowsum + requant params from flag-selected int8 weights.
__global__ void ql_prep8_kernel(const void* worig, const int8_t* w8p, const int* qbias,
                                const float* wscale, int* ws) {
    const int fb = __builtin_amdgcn_readfirstlane(ws[1]);
    const int8_t* w8 = fb ? (const int8_t*)worig : w8p;

    const int lane = threadIdx.x & 63;
    const int wid  = threadIdx.x >> 6;
    const int n = blockIdx.x * 4 + wid;

    const int32x4* row = (const int32x4*)(w8 + (size_t)n * K_DIM);
    int s = 0;
    for (int c = lane; c < K_DIM / 16; c += 64) {
        int32x4 v = row[c];
#pragma unroll
        for (int j = 0; j < 4; ++j) {
            int w = (j == 0) ? v.x : (j == 1) ? v.y : (j == 2) ? v.z : v.w;
            s += (int)(int8_t)(w) + (int)(int8_t)(w >> 8)
               + (int)(int8_t)(w >> 16) + (w >> 24);
        }
    }
#pragma unroll
    for (int off = 32; off > 0; off >>= 1) s += __shfl_down(s, off, 64);

    if (lane == 0) {
        ws[16 + n] = qbias[n] + 3 * s;                       // qbias - rowsum*Zin, Zin=-3
        float folded = (0.05f * wscale[n]) / 0.1f;           // in (0,1)
        int fbits = (int)(7.0f - ceilf(log2f(folded)));
        int isc = (int)rintf(folded * exp2f((float)fbits));  // nearest-even == np.round
        ws[16 + N_DIM + n] = isc;
        ws[16 + 2 * N_DIM + n] = fbits;
    }
}

// Fallback prep (ws too small): reads original W, flag-based.
__global__ void ql_prep_kernel(const void* wptr, const int* qbias,
                               const float* wscale, int* ws) {
    const int lane = threadIdx.x & 63;
    const int wid  = threadIdx.x >> 6;
    const int n = blockIdx.x * 4 + wid;
    const int b8 = __builtin_amdgcn_readfirstlane(ws[1]);

    int s = 0;
    if (b8) {
        const int32x4* row = (const int32x4*)((const int8_t*)wptr + (size_t)n * K_DIM);
        for (int c = lane; c < K_DIM / 16; c += 64) {
            int32x4 v = row[c];
#pragma unroll
            for (int j = 0; j < 4; ++j) {
                int w = (j == 0) ? v.x : (j == 1) ? v.y : (j == 2) ? v.z : v.w;
                s += (int)(int8_t)(w) + (int)(int8_t)(w >> 8)
                   + (int)(int8_t)(w >> 16) + (w >> 24);
            }
        }
    } else {
        const int32x4* row = (const int32x4*)((const int*)wptr + (size_t)n * K_DIM);
        for (int c = lane; c < K_DIM / 4; c += 64) {
            int32x4 v = row[c];
            s += v.x + v.y + v.z + v.w;
        }
    }
#pragma unroll
    for (int off = 32; off > 0; off >>= 1) s += __shfl_down(s, off, 64);

    if (lane == 0) {
        ws[16 + n] = qbias[n] + 3 * s;
        float folded = (0.05f * wscale[n]) / 0.1f;
        int fbits = (int)(7.0f - ceilf(log2f(folded)));
        int isc = (int)rintf(folded * exp2f((float)fbits));
        ws[16 + N_DIM + n] = isc;
        ws[16 + 2 * N_DIM + n] = fbits;
    }
}

// Fallback epilogue (128x128 path): requantize acc tile and store int32.
__device__ __forceinline__ void ql_epilogue(int32x4 acc[4][4], const int* ws,
                                            int* out, int bm, int bn,
                                            int wm, int wn, int qm, int qh) {
    const int* qb  = ws + 16;
    const int* isc = ws + 16 + N_DIM;
    const int* fbt = ws + 16 + 2 * N_DIM;
#pragma unroll
    for (int j = 0; j < 4; ++j) {
        const int n_g = bn * BN + wn + j * 16 + qm;
        const int b0 = qb[n_g];
        const int s0 = isc[n_g];
        const int f0 = fbt[n_g];
#pragma unroll
        for (int i = 0; i < 4; ++i) {
            const int m_base = bm * BM + wm + i * 16 + qh * 4;
#pragma unroll
            for (int r = 0; r < 4; ++r) {
                int v = ((r == 0) ? acc[i][j].x : (r == 1) ? acc[i][j].y
                        : (r == 2) ? acc[i][j].z : acc[i][j].w) + b0;
                long long p = (long long)v * (long long)s0;
                int o = (int)(p >> f0) - 5;            // + OUTPUT_ZERO_POINT (-5)
                o = o < -128 ? -128 : (o > 127 ? 127 : o);
                out[(size_t)(m_base + r) * N_DIM + n_g] = o;
            }
        }
    }
}

// -------- fast path: 256x256 double-buffered single-barrier GEMM, 32x32x32 i8 --------
// LDS: row-major 128-B rows; chunk swizzle f(row) = (row&7) ^ ((row>>3)&3) so that
// within any 32-lane quantum the 4 lanes reading the same logical k-chunk (rows
// r, r+8, r+16, r+24) land on 4 distinct bank sets. Stage source pre-applies f.
// Per tile: issue all 24 ds_reads + 8 stage loads (next tile -> other buffer),
// then 32 MFMAs with compiler partial lgkm waits; ONE __syncthreads() per tile
// (its vmcnt/lgkm drain is the exact ring hazard requirement; stage loads have a
// full tile (~2300cy >> 900cy HBM) to land, so the drain is ~free).

#define TILE2(BUF, TT) do { \
    _Pragma("unroll") for (int ml = 0; ml < 2; ++ml) \
    _Pragma("unroll") for (int kc = 0; kc < 4; ++kc) \
        afL[ml][kc] = LA[BUF][baseAe[kc] + ml * 256]; \
    _Pragma("unroll") for (int kc = 0; kc < 4; ++kc) \
        bf0[kc] = LB[BUF][baseBe[kc]]; \
    _Pragma("unroll") for (int kc = 0; kc < 4; ++kc) \
        bf1[kc] = LB[BUF][baseBe[kc] + 256]; \
    _Pragma("unroll") for (int ml = 0; ml < 2; ++ml) \
    _Pragma("unroll") for (int kc = 0; kc < 4; ++kc) \
        afH[ml][kc] = LA[BUF][baseAe[kc] + 512 + ml * 256]; \
    if ((TT) + 1 < NKT) { \
        _Pragma("unroll") for (int h2 = 0; h2 < 4; ++h2) { \
            async_copy16(gA + (size_t)((TT) + 1) * 128 + (size_t)h2 * 262144, \
                         &LA[(BUF) ^ 1][h2 * 512 + t]); \
            async_copy16(gB + (size_t)((TT) + 1) * 128 + (size_t)h2 * 262144, \
                         &LB[(BUF) ^ 1][h2 * 512 + t]); \
        } \
    } \
    __builtin_amdgcn_s_setprio(1); \
    _Pragma("unroll") for (int kc = 0; kc < 4; ++kc) \
    _Pragma("unroll") for (int ml = 0; ml < 2; ++ml) \
        acc[ml][0] = __builtin_amdgcn_mfma_i32_32x32x32_i8(afL[ml][kc], bf0[kc], acc[ml][0], 0, 0, 0); \
    _Pragma("unroll") for (int kc = 0; kc < 4; ++kc) \
    _Pragma("unroll") for (int ml = 0; ml < 2; ++ml) \
        acc[ml][1] = __builtin_amdgcn_mfma_i32_32x32x32_i8(afL[ml][kc], bf1[kc], acc[ml][1], 0, 0, 0); \
    _Pragma("unroll") for (int kc = 0; kc < 4; ++kc) \
    _Pragma("unroll") for (int ml = 0; ml < 2; ++ml) \
        acc[2 + ml][0] = __builtin_amdgcn_mfma_i32_32x32x32_i8(afH[ml][kc], bf0[kc], acc[2 + ml][0], 0, 0, 0); \
    _Pragma("unroll") for (int kc = 0; kc < 4; ++kc) \
    _Pragma("unroll") for (int ml = 0; ml < 2; ++ml) \
        acc[2 + ml][1] = __builtin_amdgcn_mfma_i32_32x32x32_i8(afH[ml][kc], bf1[kc], acc[2 + ml][1], 0, 0, 0); \
    __builtin_amdgcn_s_setprio(0); \
    __syncthreads(); \
} while (0)

__global__ __launch_bounds__(512, 2)
void ql_gemm8_kernel(const void* a0, const int8_t* a8,
                     const void* b0, const int8_t* w8,
                     const int* ws, int* out) {
    __shared__ int32x4 LA[2][2048];   // 2 x 32 KB
    __shared__ int32x4 LB[2][2048];   // 2 x 32 KB (total 128 KB)

    const int fa = __builtin_amdgcn_readfirstlane(ws[0]);
    const int fb = __builtin_amdgcn_readfirstlane(ws[1]);
    const int8_t* aptr = fa ? (const int8_t*)a0 : a8;
    const int8_t* bptr = fb ? (const int8_t*)b0 : w8;

    const int t    = threadIdx.x;     // 512 threads = 8 waves
    const int lane = t & 63;
    const int wid  = t >> 6;          // 0..7
    const int wr   = wid >> 2;        // 0..1  M-half (128 rows)
    const int wc   = wid & 3;         // 0..3  N-quarter (64 cols)
    const int l31  = lane & 31;
    const int hi   = lane >> 5;

    const int bn = blockIdx.x;        // N/256 = 16
    const int bm = blockIdx.y;        // M/256 = 32
    const int arow0 = bm * BM2;
    const int brow0 = bn * BN2;

    // LDS frag bases (units of int32x4). phys = logical ^ f(row),
    // f(row) = (row&7) ^ ((row>>3)&3); for frag rows f = (lane&7) ^ ((l31>>3)&3).
    const int fr = (lane & 7) ^ ((l31 >> 3) & 3);
    int baseAe[4], baseBe[4];
#pragma unroll
    for (int kc = 0; kc < 4; ++kc) {
        const int phys = (kc * 2 + hi) ^ fr;
        baseAe[kc] = (wr * 128 + l31) * 8 + phys;
        baseBe[kc] = (wc * 64  + l31) * 8 + phys;
    }

    // Stage source pre-swizzle: thread t writes phys chunk (t&7) of row
    // h2*64 + (t>>3); logical col = (t&7) ^ f(row), f = ((t>>3)&7) ^ ((t>>6)&3).
    const int colg = (t & 7) ^ ((t >> 3) & 7) ^ ((t >> 6) & 3);
    const int8_t* gA = aptr + (size_t)(arow0 + (t >> 3)) * K_DIM + colg * 16;
    const int8_t* gB = bptr + (size_t)(brow0 + (t >> 3)) * K_DIM + colg * 16;

    int32x16 acc[4][2] = {};
    int32x4 afL[2][4], afH[2][4], bf0[4], bf1[4];

    // prologue: stage T0 -> buf 0 (8 loads/thread)
#pragma unroll
    for (int h2 = 0; h2 < 4; ++h2) {
        async_copy16(gA + (size_t)h2 * 262144, &LA[0][h2 * 512 + t]);
        async_copy16(gB + (size_t)h2 * 262144, &LB[0][h2 * 512 + t]);
    }
    __syncthreads();

#pragma unroll 1
    for (int T = 0; T < NKT; T += 2) {
        TILE2(0, T);
        TILE2(1, T + 1);
    }

    // epilogue: requantize + store (C/D map: col=lane&31, row=(reg&3)+8*(reg>>2)+4*hi)
    const int* qb  = ws + 16;
    const int* isc = ws + 16 + N_DIM;
    const int* fbt = ws + 16 + 2 * N_DIM;
#pragma unroll
    for (int j = 0; j < 2; ++j) {
        const int n_g = bn * BN2 + wc * 64 + j * 32 + l31;
        const int b0r = qb[n_g];
        const int s0r = isc[n_g];
        const int f0r = fbt[n_g];
#pragma unroll
        for (int i = 0; i < 4; ++i) {
            const int m0 = bm * BM2 + wr * 128 + i * 32 + hi * 4;
#pragma unroll
            for (int reg = 0; reg < 16; ++reg) {
                const int row = (reg & 3) + 8 * (reg >> 2);
                int v = acc[i][j][reg] + b0r;
                long long p = (long long)v * (long long)s0r;
                int o = (int)(p >> f0r) - 5;           // + OUTPUT_ZERO_POINT (-5)
                o = o < -128 ? -128 : (o > 127 ? 127 : o);
                out[(size_t)(m0 + row) * N_DIM + n_g] = o;
            }
        }
    }
}

// Fallback (ws too small): verified 128x128 kernel, packs in-loop.
__global__ __launch_bounds__(256)
void ql_gemm_fb_kernel(const void* aptr, const void* bptr, const int* ws, int* out) {
    __shared__ int32x4 Als[BM * BK / 16];
    __shared__ int32x4 Bls[BN * BK / 16];

    const int a8 = __builtin_amdgcn_readfirstlane(ws[0]);
    const int b8 = __builtin_amdgcn_readfirstlane(ws[1]);

    const int t    = threadIdx.x;
    const int lane = t & 63;
    const int wid  = t >> 6;
    const int bn = blockIdx.x;
    const int bm = blockIdx.y;

    const int wm = (wid >> 1) * 64;
    const int wn = (wid & 1) * 64;
    const int qm = lane & 15;
    const int qh = lane >> 4;

    int32x4 acc[4][4] = {};

    for (int kt = 0; kt < K_DIM / BK; ++kt) {
        __syncthreads();
        const int k0 = kt * BK;
#pragma unroll
        for (int r = 0; r < 4; ++r) {
            const int c    = r * 256 + t;
            const int row  = c >> 3;
            const int colg = (c & 7) ^ (row & 7);
            const size_t offA = (size_t)(bm * BM + row) * K_DIM + k0 + colg * 16;
            const size_t offB = (size_t)(bn * BN + row) * K_DIM + k0 + colg * 16;
            if (a8) async_copy16((const int8_t*)aptr + offA, &Als[c]);
            else    Als[c] = pack16((const int*)aptr + offA);
            if (b8) async_copy16((const int8_t*)bptr + offB, &Bls[c]);
            else    Bls[c] = pack16((const int*)bptr + offB);
        }
        __syncthreads();

#pragma unroll
        for (int s = 0; s < 2; ++s) {
            const int colk = s * 4 + qh;
            int32x4 af[4], bf[4];
#pragma unroll
            for (int i = 0; i < 4; ++i) {
                const int ra = wm + i * 16 + qm;
                const int rb = wn + i * 16 + qm;
                af[i] = Als[ra * 8 + (colk ^ (ra & 7))];
                bf[i] = Bls[rb * 8 + (colk ^ (rb & 7))];
            }
#pragma unroll
            for (int i = 0; i < 4; ++i)
#pragma unroll
                for (int j = 0; j < 4; ++j)
                    acc[i][j] = __builtin_amdgcn_mfma_i32_16x16x64_i8(
                        af[i], bf[j], acc[i][j], 0, 0, 0);
        }
    }
    ql_epilogue(acc, ws, out, bm, bn, wm, wn, qm, qh);
}

extern "C" void kernel_launch(void* const* d_in, const int* in_sizes, int n_in,
                              void* d_out, int out_size, void* d_ws, size_t ws_size,
                              hipStream_t stream) {
    const void* qin    = d_in[0];
    const void* qwt    = d_in[1];
    const int* qbias   = (const int*)d_in[2];
    const float* wscal = (const float*)d_in[3];
    int* ws  = (int*)d_ws;
    int* out = (int*)d_out;

    hipLaunchKernelGGL(ql_detect_kernel, dim3(1), dim3(64), 0, stream,
                       (const int*)qin, (const int*)qwt, ws);

    const size_t need = 65536 + (size_t)M_DIM * K_DIM + (size_t)N_DIM * K_DIM;
    if (ws_size >= need) {
        int8_t* a8 = (int8_t*)d_ws + 65536;
        int8_t* w8 = a8 + (size_t)M_DIM * K_DIM;
        const long ndwA = (long)M_DIM * K_DIM / 4;   // packed output dwords
        const long ndwW = (long)N_DIM * K_DIM / 4;
        const long ndwT = ndwA + ndwW;
        hipLaunchKernelGGL(ql_pack2_kernel, dim3((unsigned)(ndwT / (256 * 4))), dim3(256),
                           0, stream, qwt, (int*)w8, qin, (int*)a8, ws, ndwW, ndwA);
        hipLaunchKernelGGL(ql_prep8_kernel, dim3(N_DIM / 4), dim3(256), 0, stream,
                           qwt, w8, qbias, wscal, ws);
        hipLaunchKernelGGL(ql_gemm8_kernel, dim3(N_DIM / BN2, M_DIM / BM2), dim3(512),
                           0, stream, qin, a8, qwt, w8, ws, out);
    } else {
        hipLaunchKernelGGL(ql_prep_kernel, dim3(N_DIM / 4), dim3(256), 0, stream,
                           qwt, qbias, wscal, ws);
        hipLaunchKernelGGL(ql_gemm_fb_kernel, dim3(N_DIM / BN, M_DIM / BM), dim3(256), 0, stream,
                           qin, qwt, ws, out);
    }
}

// Round 4
// 409.465 us; speedup vs baseline: 1.0406x; 1.0121x over previous
//
#include <hip/hip_runtime.h>
#include <cstdint>
#include <cstddef>

#define M_DIM 8192
#define N_DIM 4096
#define K_DIM 4096

// fallback-path tile (128x128, verified)
#define BM 128
#define BN 128
#define BK 128

// fast-path tile
#define BM2 256
#define BN2 256
#define BK2 128
#define NKT (K_DIM / BK2)   // 32

typedef int int32x4  __attribute__((ext_vector_type(4)));
typedef int int32x16 __attribute__((ext_vector_type(16)));

// ws layout:
//   int32 header (64 KB):
//     [0] = flagA (1 -> source already packed int8, 0 -> widened int32)
//     [1] = flagB
//     [16 .. 16+N)      qb (shifted bias)
//     [16+N .. 16+2N)   int_scale
//     [16+2N .. 16+3N)  frac_bits
//   byte 65536:           A8  (M*K int8)  (used when flagA==0)
//   byte 65536 + M*K:     W8  (N*K int8)  (used when flagB==0)

typedef __attribute__((address_space(1))) const void* gas_cptr;
typedef __attribute__((address_space(3))) void* las_ptr;

__device__ __forceinline__ void async_copy16(const void* g, void* l) {
    __builtin_amdgcn_global_load_lds((gas_cptr)g, (las_ptr)l, 16, 0, 0);
}

__device__ __forceinline__ int32x4 pack16(const int* p) {
    const int32x4* v = (const int32x4*)p;
    int32x4 w0 = v[0], w1 = v[1], w2 = v[2], w3 = v[3];
    int32x4 r;
    r.x = (w0.x & 0xFF) | ((w0.y & 0xFF) << 8) | ((w0.z & 0xFF) << 16) | (w0.w << 24);
    r.y = (w1.x & 0xFF) | ((w1.y & 0xFF) << 8) | ((w1.z & 0xFF) << 16) | (w1.w << 24);
    r.z = (w2.x & 0xFF) | ((w2.y & 0xFF) << 8) | ((w2.z & 0xFF) << 16) | (w2.w << 24);
    r.w = (w3.x & 0xFF) | ((w3.y & 0xFF) << 8) | ((w3.z & 0xFF) << 16) | (w3.w << 24);
    return r;
}

__global__ void ql_detect_kernel(const int* a, const int* b, int* ws) {
    int t = threadIdx.x;  // 64 threads
    int fa = 0, fb = 0;
    for (int i = t; i < 4096; i += 64) {
        int va = a[i]; if (va > 127 || va < -128) fa = 1;
        int vb = b[i]; if (vb > 127 || vb < -128) fb = 1;
    }
    unsigned long long ba = __ballot(fa);
    unsigned long long bb = __ballot(fb);
    if (t == 0) { ws[0] = ba ? 1 : 0; ws[1] = bb ? 1 : 0; }
}

// Merged pack, wide-store version: thread reads 64 B (4 x dwordx4, 64-B lane
// stride), writes one int32x4 (16 B, unit stride). Blocks [0,4096) -> W,
// [4096,12288) -> A. Early-exit when the corresponding flag says packed.
#define PACK_WBLOCKS 4096   // ndwW / 1024
__global__ __launch_bounds__(256)
void ql_pack2_kernel(const void* wsrc, int* wdst, const void* asrc, int* adst,
                     const int* ws) {
    const int fA = __builtin_amdgcn_readfirstlane(ws[0]);
    const int fW = __builtin_amdgcn_readfirstlane(ws[1]);
    const int bid = blockIdx.x;
    const int32x4* src;
    int32x4* dst;
    long base;
    if (bid < PACK_WBLOCKS) {
        if (fW) return;
        src = (const int32x4*)wsrc; dst = (int32x4*)wdst;
        base = (long)bid * 1024;
    } else {
        if (fA) return;
        src = (const int32x4*)asrc; dst = (int32x4*)adst;
        base = (long)(bid - PACK_WBLOCKS) * 1024;
    }
    const long d0 = base + (long)threadIdx.x * 4;   // first output dword index
    int32x4 o;
#pragma unroll
    for (int k = 0; k < 4; ++k) {
        int32x4 v = src[d0 + k];   // 16 B = 4 ints = 1 packed output dword
        ((int*)&o)[k] = (v.x & 0xFF) | ((v.y & 0xFF) << 8)
                      | ((v.z & 0xFF) << 16) | (v.w << 24);
    }
    dst[d0 >> 2] = o;
}

// Fast-path prep: rowsum + requant params from flag-selected int8 weights.
__global__ void ql_prep8_kernel(const void* worig, const int8_t* w8p, const int* qbias,
                                const float* wscale, int* ws) {
    const int fb = __builtin_amdgcn_readfirstlane(ws[1]);
    const int8_t* w8 = fb ? (const int8_t*)worig : w8p;

    const int lane = threadIdx.x & 63;
    const int wid  = threadIdx.x >> 6;
    const int n = blockIdx.x * 4 + wid;

    const int32x4* row = (const int32x4*)(w8 + (size_t)n * K_DIM);
    int s = 0;
    for (int c = lane; c < K_DIM / 16; c += 64) {
        int32x4 v = row[c];
#pragma unroll
        for (int j = 0; j < 4; ++j) {
            int w = (j == 0) ? v.x : (j == 1) ? v.y : (j == 2) ? v.z : v.w;
            s += (int)(int8_t)(w) + (int)(int8_t)(w >> 8)
               + (int)(int8_t)(w >> 16) + (w >> 24);
        }
    }
#pragma unroll
    for (int off = 32; off > 0; off >>= 1) s += __shfl_down(s, off, 64);

    if (lane == 0) {
        ws[16 + n] = qbias[n] + 3 * s;                       // qbias - rowsum*Zin, Zin=-3
        float folded = (0.05f * wscale[n]) / 0.1f;           // in (0,1)
        int fbits = (int)(7.0f - ceilf(log2f(folded)));
        int isc = (int)rintf(folded * exp2f((float)fbits));  // nearest-even == np.round
        ws[16 + N_DIM + n] = isc;
        ws[16 + 2 * N_DIM + n] = fbits;
    }
}

// Fallback prep (ws too small): reads original W, flag-based.
__global__ void ql_prep_kernel(const void* wptr, const int* qbias,
                               const float* wscale, int* ws) {
    const int lane = threadIdx.x & 63;
    const int wid  = threadIdx.x >> 6;
    const int n = blockIdx.x * 4 + wid;
    const int b8 = __builtin_amdgcn_readfirstlane(ws[1]);

    int s = 0;
    if (b8) {
        const int32x4* row = (const int32x4*)((const int8_t*)wptr + (size_t)n * K_DIM);
        for (int c = lane; c < K_DIM / 16; c += 64) {
            int32x4 v = row[c];
#pragma unroll
            for (int j = 0; j < 4; ++j) {
                int w = (j == 0) ? v.x : (j == 1) ? v.y : (j == 2) ? v.z : v.w;
                s += (int)(int8_t)(w) + (int)(int8_t)(w >> 8)
                   + (int)(int8_t)(w >> 16) + (w >> 24);
            }
        }
    } else {
        const int32x4* row = (const int32x4*)((const int*)wptr + (size_t)n * K_DIM);
        for (int c = lane; c < K_DIM / 4; c += 64) {
            int32x4 v = row[c];
            s += v.x + v.y + v.z + v.w;
        }
    }
#pragma unroll
    for (int off = 32; off > 0; off >>= 1) s += __shfl_down(s, off, 64);

    if (lane == 0) {
        ws[16 + n] = qbias[n] + 3 * s;
        float folded = (0.05f * wscale[n]) / 0.1f;
        int fbits = (int)(7.0f - ceilf(log2f(folded)));
        int isc = (int)rintf(folded * exp2f((float)fbits));
        ws[16 + N_DIM + n] = isc;
        ws[16 + 2 * N_DIM + n] = fbits;
    }
}

// Fallback epilogue (128x128 path): requantize acc tile and store int32.
__device__ __forceinline__ void ql_epilogue(int32x4 acc[4][4], const int* ws,
                                            int* out, int bm, int bn,
                                            int wm, int wn, int qm, int qh) {
    const int* qb  = ws + 16;
    const int* isc = ws + 16 + N_DIM;
    const int* fbt = ws + 16 + 2 * N_DIM;
#pragma unroll
    for (int j = 0; j < 4; ++j) {
        const int n_g = bn * BN + wn + j * 16 + qm;
        const int b0 = qb[n_g];
        const int s0 = isc[n_g];
        const int f0 = fbt[n_g];
#pragma unroll
        for (int i = 0; i < 4; ++i) {
            const int m_base = bm * BM + wm + i * 16 + qh * 4;
#pragma unroll
            for (int r = 0; r < 4; ++r) {
                int v = ((r == 0) ? acc[i][j].x : (r == 1) ? acc[i][j].y
                        : (r == 2) ? acc[i][j].z : acc[i][j].w) + b0;
                long long p = (long long)v * (long long)s0;
                int o = (int)(p >> f0) - 5;            // + OUTPUT_ZERO_POINT (-5)
                o = o < -128 ? -128 : (o > 127 ? 127 : o);
                out[(size_t)(m_base + r) * N_DIM + n_g] = o;
            }
        }
    }
}

// -------- fast path: 256x256 double-buffered single-barrier GEMM, 32x32x32 i8 --------
// LDS: row-major 128-B rows; chunk swizzle f(row) = (row&7) ^ ((row>>3)&3);
// stage source pre-applies f. One __syncthreads per tile (vmcnt drain = ring hazard).
// NEW (R4): bijective XCD-chunked block swizzle — each XCD owns a contiguous
// 4bm x 16bn region, ordered bm-pairs x bn, so its ~32 concurrent blocks keep
// 2 A-panels hot in private L2 and pair-share B panels (staging L3 traffic /3.7).

#define TILE2(BUF, TT) do { \
    _Pragma("unroll") for (int ml = 0; ml < 2; ++ml) \
    _Pragma("unroll") for (int kc = 0; kc < 4; ++kc) \
        afL[ml][kc] = LA[BUF][baseAe[kc] + ml * 256]; \
    _Pragma("unroll") for (int kc = 0; kc < 4; ++kc) \
        bf0[kc] = LB[BUF][baseBe[kc]]; \
    _Pragma("unroll") for (int kc = 0; kc < 4; ++kc) \
        bf1[kc] = LB[BUF][baseBe[kc] + 256]; \
    _Pragma("unroll") for (int ml = 0; ml < 2; ++ml) \
    _Pragma("unroll") for (int kc = 0; kc < 4; ++kc) \
        afH[ml][kc] = LA[BUF][baseAe[kc] + 512 + ml * 256]; \
    if ((TT) + 1 < NKT) { \
        _Pragma("unroll") for (int h2 = 0; h2 < 4; ++h2) { \
            async_copy16(gA + (size_t)((TT) + 1) * 128 + (size_t)h2 * 262144, \
                         &LA[(BUF) ^ 1][h2 * 512 + t]); \
            async_copy16(gB + (size_t)((TT) + 1) * 128 + (size_t)h2 * 262144, \
                         &LB[(BUF) ^ 1][h2 * 512 + t]); \
        } \
    } \
    __builtin_amdgcn_s_setprio(1); \
    _Pragma("unroll") for (int kc = 0; kc < 4; ++kc) \
    _Pragma("unroll") for (int ml = 0; ml < 2; ++ml) \
        acc[ml][0] = __builtin_amdgcn_mfma_i32_32x32x32_i8(afL[ml][kc], bf0[kc], acc[ml][0], 0, 0, 0); \
    _Pragma("unroll") for (int kc = 0; kc < 4; ++kc) \
    _Pragma("unroll") for (int ml = 0; ml < 2; ++ml) \
        acc[ml][1] = __builtin_amdgcn_mfma_i32_32x32x32_i8(afL[ml][kc], bf1[kc], acc[ml][1], 0, 0, 0); \
    _Pragma("unroll") for (int kc = 0; kc < 4; ++kc) \
    _Pragma("unroll") for (int ml = 0; ml < 2; ++ml) \
        acc[2 + ml][0] = __builtin_amdgcn_mfma_i32_32x32x32_i8(afH[ml][kc], bf0[kc], acc[2 + ml][0], 0, 0, 0); \
    _Pragma("unroll") for (int kc = 0; kc < 4; ++kc) \
    _Pragma("unroll") for (int ml = 0; ml < 2; ++ml) \
        acc[2 + ml][1] = __builtin_amdgcn_mfma_i32_32x32x32_i8(afH[ml][kc], bf1[kc], acc[2 + ml][1], 0, 0, 0); \
    __builtin_amdgcn_s_setprio(0); \
    __syncthreads(); \
} while (0)

__global__ __launch_bounds__(512, 2)
void ql_gemm8_kernel(const void* a0, const int8_t* a8,
                     const void* b0, const int8_t* w8,
                     const int* ws, int* out) {
    __shared__ int32x4 LA[2][2048];   // 2 x 32 KB
    __shared__ int32x4 LB[2][2048];   // 2 x 32 KB (total 128 KB)

    const int fa = __builtin_amdgcn_readfirstlane(ws[0]);
    const int fb = __builtin_amdgcn_readfirstlane(ws[1]);
    const int8_t* aptr = fa ? (const int8_t*)a0 : a8;
    const int8_t* bptr = fb ? (const int8_t*)b0 : w8;

    const int t    = threadIdx.x;     // 512 threads = 8 waves
    const int lane = t & 63;
    const int wid  = t >> 6;          // 0..7
    const int wr   = wid >> 2;        // 0..1  M-half (128 rows)
    const int wc   = wid & 3;         // 0..3  N-quarter (64 cols)
    const int l31  = lane & 31;
    const int hi   = lane >> 5;

    // XCD-chunked bijective swizzle (nwg = 512 = 8 XCD x 64):
    //   xcd owns bm in [xcd*4, xcd*4+4), ordered as bm-pairs x bn.
    const int flat = blockIdx.y * gridDim.x + blockIdx.x;   // 0..511
    const int xcd  = flat & 7;
    const int lid  = flat >> 3;       // 0..63, temporal order within XCD
    const int g    = lid >> 5;        // bm-pair index (0..1)
    const int r    = lid & 31;
    const int bm   = xcd * 4 + g * 2 + (r & 1);   // 0..31
    const int bn   = r >> 1;                      // 0..15

    const int arow0 = bm * BM2;
    const int brow0 = bn * BN2;

    // LDS frag bases (units of int32x4). phys = logical ^ f(row),
    // f(row) = (row&7) ^ ((row>>3)&3); for frag rows f = (lane&7) ^ ((l31>>3)&3).
    const int fr = (lane & 7) ^ ((l31 >> 3) & 3);
    int baseAe[4], baseBe[4];
#pragma unroll
    for (int kc = 0; kc < 4; ++kc) {
        const int phys = (kc * 2 + hi) ^ fr;
        baseAe[kc] = (wr * 128 + l31) * 8 + phys;
        baseBe[kc] = (wc * 64  + l31) * 8 + phys;
    }

    // Stage source pre-swizzle: thread t writes phys chunk (t&7) of row
    // h2*64 + (t>>3); logical col = (t&7) ^ f(row), f = ((t>>3)&7) ^ ((t>>6)&3).
    const int colg = (t & 7) ^ ((t >> 3) & 7) ^ ((t >> 6) & 3);
    const int8_t* gA = aptr + (size_t)(arow0 + (t >> 3)) * K_DIM + colg * 16;
    const int8_t* gB = bptr + (size_t)(brow0 + (t >> 3)) * K_DIM + colg * 16;

    int32x16 acc[4][2] = {};
    int32x4 afL[2][4], afH[2][4], bf0[4], bf1[4];

    // prologue: stage T0 -> buf 0 (8 loads/thread)
#pragma unroll
    for (int h2 = 0; h2 < 4; ++h2) {
        async_copy16(gA + (size_t)h2 * 262144, &LA[0][h2 * 512 + t]);
        async_copy16(gB + (size_t)h2 * 262144, &LB[0][h2 * 512 + t]);
    }
    __syncthreads();

#pragma unroll 1
    for (int T = 0; T < NKT; T += 2) {
        TILE2(0, T);
        TILE2(1, T + 1);
    }

    // epilogue: requantize + store (C/D map: col=lane&31, row=(reg&3)+8*(reg>>2)+4*hi)
    const int* qb  = ws + 16;
    const int* isc = ws + 16 + N_DIM;
    const int* fbt = ws + 16 + 2 * N_DIM;
#pragma unroll
    for (int j = 0; j < 2; ++j) {
        const int n_g = bn * BN2 + wc * 64 + j * 32 + l31;
        const int b0r = qb[n_g];
        const int s0r = isc[n_g];
        const int f0r = fbt[n_g];
#pragma unroll
        for (int i = 0; i < 4; ++i) {
            const int m0 = bm * BM2 + wr * 128 + i * 32 + hi * 4;
#pragma unroll
            for (int reg = 0; reg < 16; ++reg) {
                const int row = (reg & 3) + 8 * (reg >> 2);
                int v = acc[i][j][reg] + b0r;
                long long p = (long long)v * (long long)s0r;
                int o = (int)(p >> f0r) - 5;           // + OUTPUT_ZERO_POINT (-5)
                o = o < -128 ? -128 : (o > 127 ? 127 : o);
                out[(size_t)(m0 + row) * N_DIM + n_g] = o;
            }
        }
    }
}

// Fallback (ws too small): verified 128x128 kernel, packs in-loop.
__global__ __launch_bounds__(256)
void ql_gemm_fb_kernel(const void* aptr, const void* bptr, const int* ws, int* out) {
    __shared__ int32x4 Als[BM * BK / 16];
    __shared__ int32x4 Bls[BN * BK / 16];

    const int a8 = __builtin_amdgcn_readfirstlane(ws[0]);
    const int b8 = __builtin_amdgcn_readfirstlane(ws[1]);

    const int t    = threadIdx.x;
    const int lane = t & 63;
    const int wid  = t >> 6;
    const int bn = blockIdx.x;
    const int bm = blockIdx.y;

    const int wm = (wid >> 1) * 64;
    const int wn = (wid & 1) * 64;
    const int qm = lane & 15;
    const int qh = lane >> 4;

    int32x4 acc[4][4] = {};

    for (int kt = 0; kt < K_DIM / BK; ++kt) {
        __syncthreads();
        const int k0 = kt * BK;
#pragma unroll
        for (int r = 0; r < 4; ++r) {
            const int c    = r * 256 + t;
            const int row  = c >> 3;
            const int colg = (c & 7) ^ (row & 7);
            const size_t offA = (size_t)(bm * BM + row) * K_DIM + k0 + colg * 16;
            const size_t offB = (size_t)(bn * BN + row) * K_DIM + k0 + colg * 16;
            if (a8) async_copy16((const int8_t*)aptr + offA, &Als[c]);
            else    Als[c] = pack16((const int*)aptr + offA);
            if (b8) async_copy16((const int8_t*)bptr + offB, &Bls[c]);
            else    Bls[c] = pack16((const int*)bptr + offB);
        }
        __syncthreads();

#pragma unroll
        for (int s = 0; s < 2; ++s) {
            const int colk = s * 4 + qh;
            int32x4 af[4], bf[4];
#pragma unroll
            for (int i = 0; i < 4; ++i) {
                const int ra = wm + i * 16 + qm;
                const int rb = wn + i * 16 + qm;
                af[i] = Als[ra * 8 + (colk ^ (ra & 7))];
                bf[i] = Bls[rb * 8 + (colk ^ (rb & 7))];
            }
#pragma unroll
            for (int i = 0; i < 4; ++i)
#pragma unroll
                for (int j = 0; j < 4; ++j)
                    acc[i][j] = __builtin_amdgcn_mfma_i32_16x16x64_i8(
                        af[i], bf[j], acc[i][j], 0, 0, 0);
        }
    }
    ql_epilogue(acc, ws, out, bm, bn, wm, wn, qm, qh);
}

extern "C" void kernel_launch(void* const* d_in, const int* in_sizes, int n_in,
                              void* d_out, int out_size, void* d_ws, size_t ws_size,
                              hipStream_t stream) {
    const void* qin    = d_in[0];
    const void* qwt    = d_in[1];
    const int* qbias   = (const int*)d_in[2];
    const float* wscal = (const float*)d_in[3];
    int* ws  = (int*)d_ws;
    int* out = (int*)d_out;

    hipLaunchKernelGGL(ql_detect_kernel, dim3(1), dim3(64), 0, stream,
                       (const int*)qin, (const int*)qwt, ws);

    const size_t need = 65536 + (size_t)M_DIM * K_DIM + (size_t)N_DIM * K_DIM;
    if (ws_size >= need) {
        int8_t* a8 = (int8_t*)d_ws + 65536;
        int8_t* w8 = a8 + (size_t)M_DIM * K_DIM;
        const unsigned packBlocks = PACK_WBLOCKS + (unsigned)((long)M_DIM * K_DIM / 4 / 1024);
        hipLaunchKernelGGL(ql_pack2_kernel, dim3(packBlocks), dim3(256),
                           0, stream, qwt, (int*)w8, qin, (int*)a8, ws);
        hipLaunchKernelGGL(ql_prep8_kernel, dim3(N_DIM / 4), dim3(256), 0, stream,
                           qwt, w8, qbias, wscal, ws);
        hipLaunchKernelGGL(ql_gemm8_kernel, dim3(N_DIM / BN2, M_DIM / BM2), dim3(512),
                           0, stream, qin, a8, qwt, w8, ws, out);
    } else {
        hipLaunchKernelGGL(ql_prep_kernel, dim3(N_DIM / 4), dim3(256), 0, stream,
                           qwt, qbias, wscal, ws);
        hipLaunchKernelGGL(ql_gemm_fb_kernel, dim3(N_DIM / BN, M_DIM / BM), dim3(256), 0, stream,
                           qin, qwt, ws, out);
    }
}